// Round 1
// baseline (843.427 us; speedup 1.0000x reference)
//
#include <hip/hip_runtime.h>
#include <math.h>

#define INV_EPS  (-20.0f)   // -1/0.05
#define TOLV     0.001f
#define MAX_ITER 50
#define BB 32
#define NN 1024
#define MM 1024

__device__ __forceinline__ float wave_max64(float v) {
    #pragma unroll
    for (int off = 32; off > 0; off >>= 1)
        v = fmaxf(v, __shfl_xor(v, off, 64));
    return v;
}
__device__ __forceinline__ float wave_sum64(float v) {
    #pragma unroll
    for (int off = 32; off > 0; off >>= 1)
        v += __shfl_xor(v, off, 64);
    return v;
}

// Row update: one wave per row r=(b,n).
// new_u[b,n] = log(src+1e-12) - logsumexp_m(-20*cost[b,n,m] + log_v[b,m])
__global__ __launch_bounds__(256) void row_kernel(
    const float* __restrict__ cost, const float* __restrict__ src,
    float* __restrict__ log_u, const float* __restrict__ log_v,
    int* __restrict__ ncv, const int* __restrict__ done)
{
    if (*done) return;
    const int wave = threadIdx.x >> 6;
    const int lane = threadIdx.x & 63;
    const int r = (blockIdx.x << 2) + wave;          // [0, B*N)
    const int b = r >> 10;

    const float4* row4 = (const float4*)(cost + ((size_t)r << 10));
    const float4* lv4  = (const float4*)(log_v + ((size_t)b << 10));

    float val[16];
    #pragma unroll
    for (int c = 0; c < 4; ++c) {
        float4 f = row4[(c << 6) + lane];
        float4 v = lv4 [(c << 6) + lane];
        val[c*4+0] = fmaf(f.x, INV_EPS, v.x);
        val[c*4+1] = fmaf(f.y, INV_EPS, v.y);
        val[c*4+2] = fmaf(f.z, INV_EPS, v.z);
        val[c*4+3] = fmaf(f.w, INV_EPS, v.w);
    }
    float mx = val[0];
    #pragma unroll
    for (int i = 1; i < 16; ++i) mx = fmaxf(mx, val[i]);
    mx = wave_max64(mx);

    float s = 0.f;
    #pragma unroll
    for (int i = 0; i < 16; ++i) s += __expf(val[i] - mx);
    s = wave_sum64(s);

    if (lane == 0) {
        float lse = mx + __logf(s);
        float nu  = __logf(src[r] + 1e-12f) - lse;
        float old = log_u[r];
        log_u[r] = nu;
        if (fabsf(nu - old) >= TOLV) *ncv = 1;   // benign same-value race
    }
}

// Col update: block covers 64 columns of one batch; 4 waves split the n range.
// new_v[b,m] = log(tgt+1e-12) - logsumexp_n(-20*cost[b,n,m] + new_u[b,n])
// Last block to finish folds the convergence flag (2 kernels/iter total).
__global__ __launch_bounds__(256) void col_kernel(
    const float* __restrict__ cost, const float* __restrict__ tgt,
    const float* __restrict__ log_u, float* __restrict__ log_v,
    int* __restrict__ ncv, int* __restrict__ done, int* __restrict__ counter)
{
    if (*done) return;
    const int wave = threadIdx.x >> 6;
    const int lane = threadIdx.x & 63;
    const int b  = blockIdx.x >> 4;
    const int m  = ((blockIdx.x & 15) << 6) + lane;
    const float* cb = cost  + ((size_t)b << 20);
    const float* ub = log_u + (b << 10);

    // online logsumexp over this wave's n-strip (stride 4), one __expf/elem
    float run_m = -INFINITY, run_s = 0.f;
    for (int n = wave; n < NN; n += 4) {
        float u = ub[n];                                   // wave-uniform, L1 hit
        float v = fmaf(cb[((size_t)n << 10) + m], INV_EPS, u);
        float d = v - run_m;                               // first iter: +inf
        float e = __expf(-fabsf(d));                       // first iter: 0
        if (d > 0.f) { run_s = fmaf(run_s, e, 1.f); run_m = v; }
        else         { run_s += e; }
    }

    __shared__ float sm[4][64], ss[4][64];
    sm[wave][lane] = run_m;
    ss[wave][lane] = run_s;
    __syncthreads();

    if (threadIdx.x < 64) {
        float m0 = sm[0][lane], m1 = sm[1][lane], m2 = sm[2][lane], m3 = sm[3][lane];
        float Mx = fmaxf(fmaxf(m0, m1), fmaxf(m2, m3));
        float S  = ss[0][lane] * __expf(m0 - Mx)
                 + ss[1][lane] * __expf(m1 - Mx)
                 + ss[2][lane] * __expf(m2 - Mx)
                 + ss[3][lane] * __expf(m3 - Mx);
        float lse = Mx + __logf(S);
        log_v[(b << 10) + m] = __logf(tgt[(b << 10) + m] + 1e-12f) - lse;
    }

    if (threadIdx.x == 0) {
        int old = atomicAdd(counter, 1);
        if (old == (int)gridDim.x - 1) {      // last block: fold convergence flag
            *counter = 0;
            if (*ncv == 0) *done = 1;
            *ncv = 0;
        }
    }
}

// out[b,n,m] = exp(log_u[b,n] - 20*cost[b,n,m] + log_v[b,m])
__global__ __launch_bounds__(256) void out_kernel(
    const float* __restrict__ cost, const float* __restrict__ log_u,
    const float* __restrict__ log_v, float* __restrict__ out)
{
    const size_t g = (size_t)blockIdx.x * 256 + threadIdx.x;  // float4 group
    const size_t e = g << 2;
    const int r  = (int)(g >> 8);        // row id b*1024+n
    const int b  = r >> 10;
    const int mi = (int)(g & 255) << 2;

    float4 c4 = *(const float4*)(cost + e);
    float4 v4 = *(const float4*)(log_v + ((size_t)b << 10) + mi);
    float  u  = log_u[r];
    float4 o;
    o.x = __expf(fmaf(c4.x, INV_EPS, u + v4.x));
    o.y = __expf(fmaf(c4.y, INV_EPS, u + v4.y));
    o.z = __expf(fmaf(c4.z, INV_EPS, u + v4.z));
    o.w = __expf(fmaf(c4.w, INV_EPS, u + v4.w));
    *(float4*)(out + e) = o;
}

extern "C" void kernel_launch(void* const* d_in, const int* in_sizes, int n_in,
                              void* d_out, int out_size, void* d_ws, size_t ws_size,
                              hipStream_t stream) {
    const float* cost = (const float*)d_in[0];
    const float* src  = (const float*)d_in[1];
    const float* tgt  = (const float*)d_in[2];
    float* out = (float*)d_out;

    float* ws     = (float*)d_ws;
    float* log_u  = ws;                  // 32768 floats
    float* log_v  = ws + 32768;          // 32768 floats
    int*   ncv     = (int*)(ws + 65536);
    int*   done    = (int*)(ws + 65537);
    int*   counter = (int*)(ws + 65538);

    // zero-init u, v, flags (ws is poisoned 0xAA before every call)
    hipMemsetAsync(d_ws, 0, (size_t)65539 * sizeof(float), stream);

    for (int it = 0; it < MAX_ITER; ++it) {
        row_kernel<<<dim3(8192), dim3(256), 0, stream>>>(cost, src, log_u, log_v, ncv, done);
        col_kernel<<<dim3(512),  dim3(256), 0, stream>>>(cost, tgt, log_u, log_v, ncv, done, counter);
    }
    out_kernel<<<dim3(32768), dim3(256), 0, stream>>>(cost, log_u, log_v, out);
}

// Round 2
// 787.069 us; speedup vs baseline: 1.0716x; 1.0716x over previous
//
#include <hip/hip_runtime.h>
#include <math.h>

#define INV_EPS  (-20.0f)   // -1/0.05
#define TOLV     0.001f
#define MAX_ITER 50
#define NBLK     256
#define NTHR     1024

__device__ __forceinline__ float wave_max64(float v) {
    #pragma unroll
    for (int o = 32; o > 0; o >>= 1) v = fmaxf(v, __shfl_xor(v, o, 64));
    return v;
}
__device__ __forceinline__ float wave_sum64(float v) {
    #pragma unroll
    for (int o = 32; o > 0; o >>= 1) v += __shfl_xor(v, o, 64);
    return v;
}

// Device-wide barrier. Safe because grid == 256 blocks of 16 waves on 256 CUs:
// all blocks are co-resident by capacity (4096 waves << 8192 capacity).
// Agent-scope acq/rel atomics emit the cross-XCD L2 writeback/invalidate.
__device__ __forceinline__ void grid_sync(int* cnt, int* gen) {
    __syncthreads();
    if (threadIdx.x == 0) {
        int g = __hip_atomic_load(gen, __ATOMIC_RELAXED, __HIP_MEMORY_SCOPE_AGENT);
        int a = __hip_atomic_fetch_add(cnt, 1, __ATOMIC_ACQ_REL, __HIP_MEMORY_SCOPE_AGENT);
        if (a == NBLK - 1) {
            __hip_atomic_store(cnt, 0, __ATOMIC_RELAXED, __HIP_MEMORY_SCOPE_AGENT);
            __hip_atomic_store(gen, g + 1, __ATOMIC_RELEASE, __HIP_MEMORY_SCOPE_AGENT);
        } else {
            while (__hip_atomic_load(gen, __ATOMIC_ACQUIRE, __HIP_MEMORY_SCOPE_AGENT) == g)
                __builtin_amdgcn_s_sleep(4);
        }
    }
    __syncthreads();
}

__global__ __launch_bounds__(NTHR, 4) void sinkhorn_persistent(
    const float* __restrict__ cost, const float* __restrict__ src,
    const float* __restrict__ tgt, float* __restrict__ out,
    float* __restrict__ log_u, float* __restrict__ log_v,
    int* __restrict__ cnt, int* __restrict__ gen, int* __restrict__ ncv)
{
    const int t    = threadIdx.x;
    const int lane = t & 63;
    const int widx = t >> 6;

    __shared__ float4 sM[32][32];
    __shared__ float4 sS[32][32];
    __shared__ int    s_conv;

    for (int it = 0; it < MAX_ITER; ++it) {
        // ---------- row phase: u[b,n] = log(src)-lse_m(-20*C + v) ----------
        {
            const int wid = blockIdx.x * 16 + widx;      // [0,4096): one wave per 8 rows
            bool flag = false;
            for (int i = 0; i < 8; ++i) {
                const int r = wid * 8 + i;               // [0, 32768)
                const int b = r >> 10;
                const float4* c4p = (const float4*)(cost + ((size_t)r << 10));
                const float4* v4p = (const float4*)(log_v + ((size_t)b << 10));
                float val[16];
                #pragma unroll
                for (int c = 0; c < 4; ++c) {
                    float4 f = c4p[(c << 6) + lane];
                    float4 vv = v4p[(c << 6) + lane];
                    val[c*4+0] = fmaf(f.x, INV_EPS, vv.x);
                    val[c*4+1] = fmaf(f.y, INV_EPS, vv.y);
                    val[c*4+2] = fmaf(f.z, INV_EPS, vv.z);
                    val[c*4+3] = fmaf(f.w, INV_EPS, vv.w);
                }
                float mx = val[0];
                #pragma unroll
                for (int i2 = 1; i2 < 16; ++i2) mx = fmaxf(mx, val[i2]);
                mx = wave_max64(mx);
                float s = 0.f;
                #pragma unroll
                for (int i2 = 0; i2 < 16; ++i2) s += __expf(val[i2] - mx);
                s = wave_sum64(s);
                if (lane == 0) {
                    float lse = mx + __logf(s);
                    float nu  = __logf(src[r] + 1e-12f) - lse;
                    float old = log_u[r];
                    log_u[r] = nu;
                    flag |= (fabsf(nu - old) >= TOLV);
                }
            }
            if (lane == 0 && flag)
                __hip_atomic_fetch_or(&ncv[it], 1, __ATOMIC_RELAXED, __HIP_MEMORY_SCOPE_AGENT);
        }
        grid_sync(cnt, gen);                              // u + ncv[it] visible

        if (t == 0)
            s_conv = (__hip_atomic_load(&ncv[it], __ATOMIC_RELAXED, __HIP_MEMORY_SCOPE_AGENT) == 0);
        __syncthreads();
        const int conv = s_conv;

        // ---------- col phase: v[b,m] = log(tgt)-lse_n(-20*C + u) ----------
        {
            const int b  = blockIdx.x >> 3;               // 32 b × 8 m-tiles
            const int mt = blockIdx.x & 7;
            const int mg = t & 31;                        // 32 col-groups of 4 (float4)
            const int ns = t >> 5;                        // 32 n-strips of 32 rows
            const float* p  = cost + ((size_t)b << 20) + (size_t)(ns * 32) * 1024
                              + (mt * 128 + mg * 4);
            const float* ub = log_u + (b << 10) + ns * 32;
            float4 rm = make_float4(-INFINITY, -INFINITY, -INFINITY, -INFINITY);
            float4 rs = make_float4(0.f, 0.f, 0.f, 0.f);
            #pragma unroll 4
            for (int k = 0; k < 32; ++k) {
                float4 c = *(const float4*)(p + (size_t)k * 1024);
                float  u = ub[k];
                float v0 = fmaf(c.x, INV_EPS, u);
                float v1 = fmaf(c.y, INV_EPS, u);
                float v2 = fmaf(c.z, INV_EPS, u);
                float v3 = fmaf(c.w, INV_EPS, u);
                float d0 = v0 - rm.x, d1 = v1 - rm.y, d2 = v2 - rm.z, d3 = v3 - rm.w;
                float e0 = __expf(-fabsf(d0)), e1 = __expf(-fabsf(d1));
                float e2 = __expf(-fabsf(d2)), e3 = __expf(-fabsf(d3));
                rs.x = (d0 > 0.f) ? fmaf(rs.x, e0, 1.f) : rs.x + e0;
                rs.y = (d1 > 0.f) ? fmaf(rs.y, e1, 1.f) : rs.y + e1;
                rs.z = (d2 > 0.f) ? fmaf(rs.z, e2, 1.f) : rs.z + e2;
                rs.w = (d3 > 0.f) ? fmaf(rs.w, e3, 1.f) : rs.w + e3;
                rm.x = (d0 > 0.f) ? v0 : rm.x;
                rm.y = (d1 > 0.f) ? v1 : rm.y;
                rm.z = (d2 > 0.f) ? v2 : rm.z;
                rm.w = (d3 > 0.f) ? v3 : rm.w;
            }
            sM[ns][mg] = rm;
            sS[ns][mg] = rs;
            __syncthreads();
            if (t < 128) {                                // one thread per column
                const int mg2 = t >> 2, comp = t & 3;
                float M = -INFINITY;
                #pragma unroll
                for (int k = 0; k < 32; ++k)
                    M = fmaxf(M, ((const float*)&sM[k][mg2])[comp]);
                float S = 0.f;
                #pragma unroll
                for (int k = 0; k < 32; ++k) {
                    float mk = ((const float*)&sM[k][mg2])[comp];
                    float sk = ((const float*)&sS[k][mg2])[comp];
                    S += sk * __expf(mk - M);
                }
                float lse = M + __logf(S);
                const int m = mt * 128 + t;
                log_v[(b << 10) + m] = __logf(tgt[(b << 10) + m] + 1e-12f) - lse;
            }
        }
        grid_sync(cnt, gen);                              // v visible

        if (conv) break;   // converging iteration commits u AND v, matching ref freeze
    }

    // ---------- epilogue: out = exp(u - 20*C + v) ----------
    {
        const int gtid = blockIdx.x * NTHR + t;
        #pragma unroll 1
        for (int i = 0; i < 32; ++i) {
            const int g  = gtid + i * (NBLK * NTHR);      // float4 group id
            const size_t e = (size_t)g << 2;
            const int r  = g >> 8;
            const int b  = r >> 10;
            const int mi = (g & 255) << 2;
            float4 c4 = *(const float4*)(cost + e);
            float4 v4 = *(const float4*)(log_v + (b << 10) + mi);
            float  u  = log_u[r];
            float4 o;
            o.x = __expf(fmaf(c4.x, INV_EPS, u + v4.x));
            o.y = __expf(fmaf(c4.y, INV_EPS, u + v4.y));
            o.z = __expf(fmaf(c4.z, INV_EPS, u + v4.z));
            o.w = __expf(fmaf(c4.w, INV_EPS, u + v4.w));
            *(float4*)(out + e) = o;
        }
    }
}

extern "C" void kernel_launch(void* const* d_in, const int* in_sizes, int n_in,
                              void* d_out, int out_size, void* d_ws, size_t ws_size,
                              hipStream_t stream) {
    const float* cost = (const float*)d_in[0];
    const float* src  = (const float*)d_in[1];
    const float* tgt  = (const float*)d_in[2];
    float* out = (float*)d_out;

    float* ws    = (float*)d_ws;
    float* log_u = ws;                    // 32768 floats
    float* log_v = ws + 32768;            // 32768 floats
    int*   cnt   = (int*)(ws + 65536);    // barrier counter
    int*   gen   = (int*)(ws + 65537);    // barrier generation
    int*   ncv   = (int*)(ws + 65538);    // ncv[50] per-iteration flags

    // zero u, v, barrier state, ncv[] (ws is poisoned 0xAA before every call)
    hipMemsetAsync(d_ws, 0, (size_t)(65536 + 2 + MAX_ITER) * sizeof(float), stream);

    sinkhorn_persistent<<<dim3(NBLK), dim3(NTHR), 0, stream>>>(
        cost, src, tgt, out, log_u, log_v, cnt, gen, ncv);
}

// Round 3
// 620.563 us; speedup vs baseline: 1.3591x; 1.2683x over previous
//
#include <hip/hip_runtime.h>
#include <math.h>

#define INV_EPS  (-20.0f)   // -1/0.05
#define TOLV     0.001f
#define MAX_ITER 50
#define NBLK     256
#define NTHR     1024

__device__ __forceinline__ float wave_sum64(float v) {
    #pragma unroll
    for (int o = 32; o > 0; o >>= 1) v += __shfl_xor(v, o, 64);
    return v;
}

// Device-wide barrier: 256 blocks × 16 waves on 256 CUs — co-resident by
// capacity. Agent-scope acq/rel emits L2 writeback/invalidate (cross-XCD safe).
__device__ __forceinline__ void grid_sync(int* cnt, int* gen) {
    __syncthreads();
    if (threadIdx.x == 0) {
        int g = __hip_atomic_load(gen, __ATOMIC_RELAXED, __HIP_MEMORY_SCOPE_AGENT);
        int a = __hip_atomic_fetch_add(cnt, 1, __ATOMIC_ACQ_REL, __HIP_MEMORY_SCOPE_AGENT);
        if (a == NBLK - 1) {
            __hip_atomic_store(cnt, 0, __ATOMIC_RELAXED, __HIP_MEMORY_SCOPE_AGENT);
            __hip_atomic_store(gen, g + 1, __ATOMIC_RELEASE, __HIP_MEMORY_SCOPE_AGENT);
        } else {
            while (__hip_atomic_load(gen, __ATOMIC_ACQUIRE, __HIP_MEMORY_SCOPE_AGENT) == g)
                __builtin_amdgcn_s_sleep(4);
        }
    }
    __syncthreads();
}

__global__ __launch_bounds__(NTHR, 4) void sinkhorn_fused(
    const float* __restrict__ cost, const float* __restrict__ src,
    const float* __restrict__ tgt, float* __restrict__ out,
    float* __restrict__ log_u, float* __restrict__ log_v,
    int* __restrict__ cnt, int* __restrict__ gen, int* __restrict__ ncv)
{
    const int t    = threadIdx.x;
    const int lane = t & 63;
    const int widx = t >> 6;
    const int b    = blockIdx.x >> 3;   // 8 blocks per batch
    const int rb   = blockIdx.x & 7;    // 128-row slab within batch

    // padded stride 17 -> 2-way-max bank aliasing (free per m136)
    __shared__ float smS[16][64][17];
    __shared__ int   s_chg, s_conv;

    // lane's columns: m = c*256 + lane*4 + j  (c<4, j<4)
    const float* vbase = log_v + (b << 10) + (lane << 2);
    const int    r0    = (b << 10) + (rb << 7) + (widx << 3);  // first of 8 rows
    const float* cbase = cost + ((size_t)r0 << 10) + (lane << 2);
    float*       wsP   = out;           // [256][1024] block partials, overwritten by epilogue

    for (int it = 0; it < MAX_ITER; ++it) {
        if (t == 0) s_chg = 0;
        __syncthreads();

        float4 vo0 = *(const float4*)(vbase);
        float4 vo1 = *(const float4*)(vbase + 256);
        float4 vo2 = *(const float4*)(vbase + 512);
        float4 vo3 = *(const float4*)(vbase + 768);
        // exp(-v_old) per slot: loop-invariant
        float h[16] = {
            __expf(-vo0.x), __expf(-vo0.y), __expf(-vo0.z), __expf(-vo0.w),
            __expf(-vo1.x), __expf(-vo1.y), __expf(-vo1.z), __expf(-vo1.w),
            __expf(-vo2.x), __expf(-vo2.y), __expf(-vo2.z), __expf(-vo2.w),
            __expf(-vo3.x), __expf(-vo3.y), __expf(-vo3.z), __expf(-vo3.w) };

        float cs[16];
        #pragma unroll
        for (int s = 0; s < 16; ++s) cs[s] = 0.f;
        bool flag = false;

        float4 f0 = *(const float4*)(cbase);
        float4 f1 = *(const float4*)(cbase + 256);
        float4 f2 = *(const float4*)(cbase + 512);
        float4 f3 = *(const float4*)(cbase + 768);

        #pragma unroll 1
        for (int i = 0; i < 8; ++i) {
            // prefetch next row (last iter re-reads row 0: branchless, always valid)
            const float* nxt = cbase + ((size_t)((i + 1) & 7) << 10);
            float4 g0 = *(const float4*)(nxt);
            float4 g1 = *(const float4*)(nxt + 256);
            float4 g2 = *(const float4*)(nxt + 512);
            float4 g3 = *(const float4*)(nxt + 768);

            float e[16];
            e[ 0] = __expf(fmaf(f0.x, INV_EPS, vo0.x));
            e[ 1] = __expf(fmaf(f0.y, INV_EPS, vo0.y));
            e[ 2] = __expf(fmaf(f0.z, INV_EPS, vo0.z));
            e[ 3] = __expf(fmaf(f0.w, INV_EPS, vo0.w));
            e[ 4] = __expf(fmaf(f1.x, INV_EPS, vo1.x));
            e[ 5] = __expf(fmaf(f1.y, INV_EPS, vo1.y));
            e[ 6] = __expf(fmaf(f1.z, INV_EPS, vo1.z));
            e[ 7] = __expf(fmaf(f1.w, INV_EPS, vo1.w));
            e[ 8] = __expf(fmaf(f2.x, INV_EPS, vo2.x));
            e[ 9] = __expf(fmaf(f2.y, INV_EPS, vo2.y));
            e[10] = __expf(fmaf(f2.z, INV_EPS, vo2.z));
            e[11] = __expf(fmaf(f2.w, INV_EPS, vo2.w));
            e[12] = __expf(fmaf(f3.x, INV_EPS, vo3.x));
            e[13] = __expf(fmaf(f3.y, INV_EPS, vo3.y));
            e[14] = __expf(fmaf(f3.z, INV_EPS, vo3.z));
            e[15] = __expf(fmaf(f3.w, INV_EPS, vo3.w));

            float s01 = e[0]+e[1],   s23 = e[2]+e[3];
            float s45 = e[4]+e[5],   s67 = e[6]+e[7];
            float s89 = e[8]+e[9],   sab = e[10]+e[11];
            float scd = e[12]+e[13], sef = e[14]+e[15];
            float s = ((s01+s23)+(s45+s67)) + ((s89+sab)+(scd+sef));
            s = wave_sum64(s);

            const int r = r0 + i;
            float u_new = __logf(src[r] + 1e-12f) - __logf(s);
            float u_old = log_u[r];
            flag |= (fabsf(u_new - u_old) >= TOLV);
            if (lane == 0) log_u[r] = u_new;

            float eu = __expf(u_new);
            #pragma unroll
            for (int k = 0; k < 16; ++k)
                cs[k] = fmaf(e[k] * eu, h[k], cs[k]);   // += exp(-20C + u_new)

            f0 = g0; f1 = g1; f2 = g2; f3 = g3;
        }

        if (lane == 0 && flag) s_chg = 1;
        #pragma unroll
        for (int s = 0; s < 16; ++s) smS[widx][lane][s] = cs[s];
        __syncthreads();

        if (t == 0 && s_chg)
            __hip_atomic_fetch_or(&ncv[it], 1, __ATOMIC_RELAXED, __HIP_MEMORY_SCOPE_AGENT);

        // combine 16 waves; thread t owns column m == t (conflict-free, coalesced)
        {
            const int L = (t >> 2) & 63;
            const int sl = ((t >> 8) << 2) | (t & 3);
            float S = 0.f;
            #pragma unroll
            for (int w = 0; w < 16; ++w) S += smS[w][L][sl];
            wsP[(size_t)(blockIdx.x << 10) + t] = S;    // partial over 128 rows
        }

        grid_sync(cnt, gen);   // u, partials, ncv[it] visible

        if (t == 0)
            s_conv = (__hip_atomic_load(&ncv[it], __ATOMIC_RELAXED, __HIP_MEMORY_SCOPE_AGENT) == 0);

        if (blockIdx.x < 32) {  // cross-block combine: batch=blockIdx, column=t
            float S = 0.f;
            #pragma unroll
            for (int r8 = 0; r8 < 8; ++r8)
                S += wsP[(size_t)(((blockIdx.x << 3) + r8) << 10) + t];
            log_v[(blockIdx.x << 10) + t] =
                __logf(tgt[(blockIdx.x << 10) + t] + 1e-12f) - __logf(S);
        }

        grid_sync(cnt, gen);   // v visible; s_conv published block-locally

        if (s_conv) break;     // converging iteration committed u AND v (ref freeze)
    }

    // epilogue: out = exp(u - 20C + v)
    {
        const int gtid = blockIdx.x * NTHR + t;
        #pragma unroll 1
        for (int i = 0; i < 32; ++i) {
            const int g  = gtid + i * (NBLK * NTHR);
            const size_t e = (size_t)g << 2;
            const int r  = g >> 8;
            const int bb = r >> 10;
            const int mi = (g & 255) << 2;
            float4 c4 = *(const float4*)(cost + e);
            float4 v4 = *(const float4*)(log_v + (bb << 10) + mi);
            float  u  = log_u[r];
            float4 o;
            o.x = __expf(fmaf(c4.x, INV_EPS, u + v4.x));
            o.y = __expf(fmaf(c4.y, INV_EPS, u + v4.y));
            o.z = __expf(fmaf(c4.z, INV_EPS, u + v4.z));
            o.w = __expf(fmaf(c4.w, INV_EPS, u + v4.w));
            *(float4*)(out + e) = o;
        }
    }
}

extern "C" void kernel_launch(void* const* d_in, const int* in_sizes, int n_in,
                              void* d_out, int out_size, void* d_ws, size_t ws_size,
                              hipStream_t stream) {
    const float* cost = (const float*)d_in[0];
    const float* src  = (const float*)d_in[1];
    const float* tgt  = (const float*)d_in[2];
    float* out = (float*)d_out;

    float* ws    = (float*)d_ws;
    float* log_u = ws;                    // 32768 floats
    float* log_v = ws + 32768;            // 32768 floats
    int*   cnt   = (int*)(ws + 65536);
    int*   gen   = (int*)(ws + 65537);
    int*   ncv   = (int*)(ws + 65538);    // [50]

    hipMemsetAsync(d_ws, 0, (size_t)(65536 + 2 + MAX_ITER) * sizeof(float), stream);

    sinkhorn_fused<<<dim3(NBLK), dim3(NTHR), 0, stream>>>(
        cost, src, tgt, out, log_u, log_v, cnt, gen, ncv);
}